// Round 6
// baseline (17.443 us; speedup 1.0000x reference)
//
#include <hip/hip_runtime.h>

#define BB 4096
#define SS 256
#define NOPS 7

typedef float f32x4 __attribute__((ext_vector_type(4)));

__device__ __forceinline__ float sel4(f32x4 v, int idx) {
    float r = v.x;
    r = (idx == 1) ? v.y : r;
    r = (idx == 2) ? v.z : r;
    r = (idx == 3) ? v.w : r;
    return r;
}

__global__ __launch_bounds__(256, 4) void arth_kernel(
    const float* __restrict__ tv_in,
    const float* __restrict__ td_in,
    const float* __restrict__ op_in,
    const float* __restrict__ if_fin,
    const float* __restrict__ if_val,
    const int* __restrict__ start_pos_p,
    float* __restrict__ out_tv,
    float* __restrict__ out_td,
    float* __restrict__ out_op,
    float* __restrict__ out_iff,
    float* __restrict__ out_iv)
{
    // One wave per row: zero LDS, zero barriers, fully wave-autonomous.
    const int t = threadIdx.x;
    const int wv = t >> 6;
    const int l  = t & 63;                       // lane
    const int r  = (blockIdx.x << 2) + wv;       // row
    const size_t rbase = (size_t)r * SS;
    const size_t obase = (size_t)r * (SS * NOPS);

    const int start_pos = *start_pos_p;
    const float fin_f = if_fin[r];               // wave-uniform value
    const float iv0   = if_val[r];

    const f32x4* in4 = (const f32x4*)(op_in + obase);
    f32x4* o4 = (f32x4*)(out_op + obase);

    // ---- Issue all loads back-to-back. ----
    // Copy path: coalesced, 7 f32x4 per lane (448 per row).
    f32x4 c0 = in4[l];
    f32x4 c1 = in4[l + 64];
    f32x4 c2 = in4[l + 128];
    f32x4 c3 = in4[l + 192];
    f32x4 c4 = in4[l + 256];
    f32x4 c5 = in4[l + 320];
    f32x4 c6 = in4[l + 384];
    // Argmax path: lane-contiguous 28 floats (positions 4l..4l+3), same
    // lines as the copy loads -> L1-hot (dual-read proven free in R5).
    const f32x4* a4 = (const f32x4*)(op_in + obase + (size_t)l * 28);
    f32x4 u0 = a4[0], u1 = a4[1], u2 = a4[2], u3 = a4[3];
    f32x4 u4 = a4[4], u5 = a4[5], u6 = a4[6];
    // tv/td as f32x4 (was dword): lane l owns positions 4l..4l+3.
    f32x4 tv4 = *(const f32x4*)(tv_in + rbase + (l << 2));
    f32x4 td4 = *(const f32x4*)(td_in + rbase + (l << 2));

    // ---- Streaming copy-out (nt: R3/R4 A/B showed nt worth ~0.7us). ----
    __builtin_nontemporal_store(c0, &o4[l]);
    __builtin_nontemporal_store(c1, &o4[l + 64]);
    __builtin_nontemporal_store(c2, &o4[l + 128]);
    __builtin_nontemporal_store(c3, &o4[l + 192]);
    __builtin_nontemporal_store(c4, &o4[l + 256]);
    __builtin_nontemporal_store(c5, &o4[l + 320]);
    __builtin_nontemporal_store(c6, &o4[l + 384]);

    // ---- Per-position argmax in registers (first-max = jnp.argmax). ----
    float af[28];
    *(f32x4*)(af +  0) = u0; *(f32x4*)(af +  4) = u1;
    *(f32x4*)(af +  8) = u2; *(f32x4*)(af + 12) = u3;
    *(f32x4*)(af + 16) = u4; *(f32x4*)(af + 20) = u5;
    *(f32x4*)(af + 24) = u6;

    int am[4];
    #pragma unroll
    for (int k = 0; k < 4; ++k) {
        const int base = k * NOPS;
        int a = 0; float best = af[base];
        #pragma unroll
        for (int q = 1; q < NOPS; ++q) {
            float v = af[base + q];
            if (v > best) { best = v; a = q; }
        }
        am[k] = a;
    }

    // ---- Wave ballots: bit l of bop[k]/bnm[k] = position 4l+k. ----
    unsigned long long bop[4], bnm[4];
    #pragma unroll
    for (int k = 0; k < 4; ++k) {
        const int p = (l << 2) + k;
        const bool vt = (p >= start_pos) && (sel4(tv4, k) > 0.5f);
        bop[k] = __ballot(vt && (am[k] != 0));
        bnm[k] = __ballot(vt && (am[k] == 0));
    }

    // First valid op position j.
    int j = 1 << 30;
    #pragma unroll
    for (int k = 0; k < 4; ++k)
        if (bop[k]) { int c = (__builtin_ctzll(bop[k]) << 2) + k; j = (c < j) ? c : j; }
    const bool hasop = (j < (1 << 30));

    // Push masks restricted to positions < j.
    unsigned long long msk[4];
    #pragma unroll
    for (int k = 0; k < 4; ++k) {
        unsigned long long mm = bnm[k];
        if (hasop) {
            int lim = j - 1 - k;
            if (lim < 0) mm = 0ull;
            else {
                int lmax = lim >> 2;
                mm &= (lmax >= 63) ? ~0ull : ((2ull << lmax) - 1ull);
            }
        }
        msk[k] = mm;
    }

    // Top-two push positions i0 (top) and i1 (second).
    int i0 = -1, k0 = -1;
    #pragma unroll
    for (int k = 0; k < 4; ++k)
        if (msk[k]) {
            int c = ((63 - __builtin_clzll(msk[k])) << 2) + k;
            if (c > i0) { i0 = c; k0 = k; }
        }
    int i1 = -1;
    if (i0 >= 0) {
        #pragma unroll
        for (int k = 0; k < 4; ++k) {
            unsigned long long mm = msk[k];
            if (k == k0) mm &= ~(1ull << (i0 >> 2));
            if (mm) {
                int c = ((63 - __builtin_clzll(mm)) << 2) + k;
                if (c > i1) i1 = c;
            }
        }
    }

    const bool finished = fin_f > 0.5f;
    const bool valid0 = iv0 > 0.5f;

    float iff, ivout;
    if (finished) {
        iff = 1.0f; ivout = iv0;
    } else if (!valid0) {
        iff = 0.0f; ivout = 0.0f;
    } else if (!hasop) {
        ivout = 1.0f; iff = (i0 >= 0 && i1 < 0) ? 1.0f : 0.0f;
    } else if (i1 >= 0) {
        // Retrieve operands/opcode via wave shuffles (indices wave-uniform).
        float h0 = __shfl(sel4(td4, i0 & 3), i0 >> 2, 64);
        float h1 = __shfl(sel4(td4, i1 & 3), i1 >> 2, 64);
        int av = am[0];
        { int ks = j & 3;
          av = (ks == 1) ? am[1] : av;
          av = (ks == 2) ? am[2] : av;
          av = (ks == 3) ? am[3] : av; }
        int opj = __shfl(av, j >> 2, 64);
        float res;
        switch (opj) {
            case 2: res = h1 + h0; break;
            case 3: res = h1 - h0; break;
            case 4: res = h1 * h0; break;
            case 5: res = h1 / (h0 + 1e-7f); break;
            case 6: res = powf(fmaxf(h1, 1e-7f), h0); break;
            default: res = 0.0f; break;   // op index 1 -> zero
        }
        // Patch td at i0, clear tv at i1 and j (predicated component moves).
        {
            const bool me = (l == (i0 >> 2)); const int ci = i0 & 3;
            td4.x = (me && ci == 0) ? res : td4.x;
            td4.y = (me && ci == 1) ? res : td4.y;
            td4.z = (me && ci == 2) ? res : td4.z;
            td4.w = (me && ci == 3) ? res : td4.w;
        }
        {
            const bool m1 = (l == (i1 >> 2)); const int c1 = i1 & 3;
            const bool mj = (l == (j >> 2));  const int cj = j & 3;
            tv4.x = ((m1 && c1 == 0) || (mj && cj == 0)) ? 0.0f : tv4.x;
            tv4.y = ((m1 && c1 == 1) || (mj && cj == 1)) ? 0.0f : tv4.y;
            tv4.z = ((m1 && c1 == 2) || (mj && cj == 2)) ? 0.0f : tv4.z;
            tv4.w = ((m1 && c1 == 3) || (mj && cj == 3)) ? 0.0f : tv4.w;
        }
        ivout = 1.0f; iff = 0.0f;
    } else {
        // Op met but stack underflow.
        ivout = 0.0f; iff = 0.0f;
    }

    // Streaming writeback, all f32x4.
    __builtin_nontemporal_store(tv4, (f32x4*)(out_tv + rbase + (l << 2)));
    __builtin_nontemporal_store(td4, (f32x4*)(out_td + rbase + (l << 2)));
    if (l == 0) {
        out_iff[r] = iff;
        out_iv[r] = ivout;
    }
}

extern "C" void kernel_launch(void* const* d_in, const int* in_sizes, int n_in,
                              void* d_out, int out_size, void* d_ws, size_t ws_size,
                              hipStream_t stream) {
    const float* tv_in = (const float*)d_in[0];   // trans_valid (B,S)
    const float* td_in = (const float*)d_in[1];   // trans_dense (B,S)
    const float* op_in = (const float*)d_in[2];   // trans_op (B,S,7)
    const float* if_fin = (const float*)d_in[3];  // if_finished (B,)
    const float* if_val = (const float*)d_in[4];  // if_valid (B,)
    const int* start_pos = (const int*)d_in[5];   // scalar

    float* out = (float*)d_out;
    float* out_tv = out;                                    // B*S
    float* out_td = out + (size_t)BB * SS;                  // B*S
    float* out_op = out + (size_t)2 * BB * SS;              // B*S*7
    float* out_iff = out + (size_t)9 * BB * SS;             // B
    float* out_iv = out + (size_t)9 * BB * SS + BB;         // B

    arth_kernel<<<BB / 4, 256, 0, stream>>>(tv_in, td_in, op_in, if_fin, if_val,
                                            start_pos, out_tv, out_td, out_op,
                                            out_iff, out_iv);
}